// Round 7
// baseline (213.526 us; speedup 1.0000x reference)
//
#include <hip/hip_runtime.h>
#include <math.h>
#include <float.h>

// Problem constants
#define NTOK 65536
#define NCB  4
#define MCODE 512
#define DIM  64

#define QST_SIZE (NTOK * NCB * DIM)        // 16777216
#define IDX_OFF  (QST_SIZE + 3)            // 16777219

// Tiles: 8 waves/block (512 thr), each wave owns 32 tokens; grid = 256 x 4
// = 1024 blocks = exactly 4 blocks/CU -> 32 waves/CU (HW max) if resident.
#define TOK_TILE  256

// ws layout (bytes):
//   ehf f16[4*16*4*512] @ 0        (262144)  hi half of 512*e, MFMA-fragment order
//   elf f16[4*16*4*512] @ 262144   (262144)  lo half, fragment order
//   d0p f32[2048]       @ 524288   (8192)    -256 * sum(e^2)  (acc C-init)
//   counts int[2048]    @ 532480   (8192)
//   lossSum f32         @ 540672
#define WS_EH 0
#define WS_EL 262144
#define WS_D0 524288
#define WS_CNT 532480
#define WS_LOSS 540672

typedef _Float16 half8 __attribute__((ext_vector_type(8)));
typedef float floatx16 __attribute__((ext_vector_type(16)));

// ---- prep: fragment-order f16 hi/lo split of 512*e, d0p = -256*|e|^2 ----
// Fragment layout for A-operand of 32x32x16: for (c, nt, ch):
//   512 f16 block; lane = h*32 + row5 holds rows (nt*32+row5), k = ch*16 + h*8 + t
__global__ __launch_bounds__(256) void prep_kernel(const float* __restrict__ emb,
                                                   _Float16* __restrict__ ehf,
                                                   _Float16* __restrict__ elf,
                                                   float* __restrict__ d0p,
                                                   int* __restrict__ counts,
                                                   float* __restrict__ lossSum) {
    int row = blockIdx.x * 256 + threadIdx.x;   // 0..2047  (grid=8)
    if (row >= NCB * MCODE) return;
    const int c   = row >> 9;
    const int n   = row & 511;
    const int nt  = n >> 5;
    const int r5  = n & 31;
    const float* src = emb + (size_t)row * DIM;

    float s = 0.f;
#pragma unroll
    for (int ch = 0; ch < 4; ++ch) {
#pragma unroll
        for (int h = 0; h < 2; ++h) {
            half8 hv, lv;
#pragma unroll
            for (int t = 0; t < 8; ++t) {
                float e = src[ch * 16 + h * 8 + t];
                s += e * e;
                float f = e * 512.0f;
                _Float16 hi = (_Float16)f;
                float r = f - (float)hi;
                hv[t] = hi;
                lv[t] = (_Float16)r;
            }
            size_t off = ((size_t)((c * 16 + nt) * 4 + ch)) * 512 + (h * 32 + r5) * 8;
            *(half8*)(ehf + off) = hv;
            *(half8*)(elf + off) = lv;
        }
    }
    d0p[row] = -256.0f * s;
    counts[row] = 0;
    if (row == 0) *lossSum = 0.f;
}

// ---- main: 32x32x16 MFMA + per-lane argmin; A staged through dbuf LDS ----
// A = codes (LDS stream shared by all 8 waves), B = tokens (persistent,
// 32 VGPR/lane). Per nt: each thread prefetches ONE float4 of chunk nt+1,
// computes nt from LDS (single 12-MFMA chain), ds_writes, one barrier.
__global__ __launch_bounds__(512) void vq_main(const float* __restrict__ x,
                                               const float* __restrict__ emb,
                                               const float* __restrict__ mask,
                                               const _Float16* __restrict__ ehf,
                                               const _Float16* __restrict__ elf,
                                               const float* __restrict__ d0p,
                                               int* __restrict__ counts,
                                               float* __restrict__ lossSum,
                                               float* __restrict__ outQ,
                                               float* __restrict__ outIdx) {
    __shared__ __align__(16) _Float16 As[2][4096];   // [buf][eh 2048 | el 2048] = 16 KB
    __shared__ __align__(16) float d0s[MCODE];       // 2 KB
    __shared__ int   Is[TOK_TILE];
    __shared__ float wls[8];

    const int tid  = threadIdx.x;         // 0..511
    const int c    = blockIdx.y;
    const int n0tk = blockIdx.x * TOK_TILE;
    const int lane = tid & 63;
    const int w    = tid >> 6;            // wave id 0..7
    const int l31  = lane & 31;           // token within wave tile / acc column
    const int hi   = lane >> 5;           // k-half for A/B, row-half for C
    const int hi4  = hi * 4;

    const _Float16* gEh = ehf + (size_t)c * (16 * 4 * 512);
    const _Float16* gEl = elf + (size_t)c * (16 * 4 * 512);

    // staging role: waves 0-3 stage eh, waves 4-7 stage el (wave-uniform)
    const int sHalf = tid >> 8;                    // 0: eh, 1: el
    const int sOff  = (tid & 255) * 8;             // halves within chunk
    const _Float16* gSrc = sHalf ? gEl : gEh;

    // ---- stage chunk 0 + d0 into LDS (loads first, overlap B-build) ----
    float4 s0 = *(const float4*)(gSrc + sOff);
    float4 dstage;
    if (tid < 128) dstage = *(const float4*)(d0p + c * MCODE + tid * 4);

    // ---- persistent B fragments (x hi/lo) for this lane's token ----
    // B col = lane&31 = token; k = ch*16 + hi*8 + t
    half8 Bh[4], Bl[4];
    {
        const float* xr = x + (size_t)(n0tk + w * 32 + l31) * (NCB * DIM) + c * DIM + hi * 8;
#pragma unroll
        for (int ch = 0; ch < 4; ++ch) {
            float fv[8];
            *(float4*)(fv)     = *(const float4*)(xr + ch * 16);
            *(float4*)(fv + 4) = *(const float4*)(xr + ch * 16 + 4);
            half8 h8, l8;
#pragma unroll
            for (int t = 0; t < 8; ++t) {
                float f = fv[t];
                _Float16 hh = (_Float16)f;
                h8[t] = hh;
                l8[t] = (_Float16)(f - (float)hh);
            }
            Bh[ch] = h8;
            Bl[ch] = l8;
        }
    }

    *(float4*)((char*)&As[0][sHalf * 2048] + (tid & 255) * 16) = s0;
    if (tid < 128) *(float4*)(&d0s[tid * 4]) = dstage;
    __syncthreads();

    float maxv = -FLT_MAX;
    int   maxn = 0;

    // ---- sweep 16 n-tiles of 32 codes, dbuf LDS + 1-ahead prefetch ----
    for (int nt = 0; nt < 16; ++nt) {
        const int p = nt & 1;

        // prefetch next chunk: ONE float4 per thread (8 KB / 512 threads)
        float4 nf;
        if (nt < 15) {
            nf = *(const float4*)(gSrc + (nt + 1) * 2048 + sOff);
        }

        // A fragment reads from LDS (16B/lane stride-1: 2-way alias, free)
        const _Float16* ah = &As[p][0] + lane * 8;
        const _Float16* al = &As[p][2048] + lane * 8;
        half8 Ah0 = *(const half8*)(ah);
        half8 Ah1 = *(const half8*)(ah + 512);
        half8 Ah2 = *(const half8*)(ah + 1024);
        half8 Ah3 = *(const half8*)(ah + 1536);
        half8 Al0 = *(const half8*)(al);
        half8 Al1 = *(const half8*)(al + 512);
        half8 Al2 = *(const half8*)(al + 1024);
        half8 Al3 = *(const half8*)(al + 1536);

        // acc C-init = -256*|e|^2 per code row (LDS broadcast reads)
        const float* dpt = &d0s[nt * 32 + hi4];
        float4 d40 = *(const float4*)(dpt);
        float4 d41 = *(const float4*)(dpt + 8);
        float4 d42 = *(const float4*)(dpt + 16);
        float4 d43 = *(const float4*)(dpt + 24);
        floatx16 acc;
        acc[0]  = d40.x; acc[1]  = d40.y; acc[2]  = d40.z; acc[3]  = d40.w;
        acc[4]  = d41.x; acc[5]  = d41.y; acc[6]  = d41.z; acc[7]  = d41.w;
        acc[8]  = d42.x; acc[9]  = d42.y; acc[10] = d42.z; acc[11] = d42.w;
        acc[12] = d43.x; acc[13] = d43.y; acc[14] = d43.z; acc[15] = d43.w;

        // 12-MFMA chain: (Ah+Al)(Bh+Bl) ≈ AhBh + AlBh + AhBl per k-chunk
        acc = __builtin_amdgcn_mfma_f32_32x32x16_f16(Ah0, Bh[0], acc, 0, 0, 0);
        acc = __builtin_amdgcn_mfma_f32_32x32x16_f16(Al0, Bh[0], acc, 0, 0, 0);
        acc = __builtin_amdgcn_mfma_f32_32x32x16_f16(Ah0, Bl[0], acc, 0, 0, 0);
        acc = __builtin_amdgcn_mfma_f32_32x32x16_f16(Ah1, Bh[1], acc, 0, 0, 0);
        acc = __builtin_amdgcn_mfma_f32_32x32x16_f16(Al1, Bh[1], acc, 0, 0, 0);
        acc = __builtin_amdgcn_mfma_f32_32x32x16_f16(Ah1, Bl[1], acc, 0, 0, 0);
        acc = __builtin_amdgcn_mfma_f32_32x32x16_f16(Ah2, Bh[2], acc, 0, 0, 0);
        acc = __builtin_amdgcn_mfma_f32_32x32x16_f16(Al2, Bh[2], acc, 0, 0, 0);
        acc = __builtin_amdgcn_mfma_f32_32x32x16_f16(Ah2, Bl[2], acc, 0, 0, 0);
        acc = __builtin_amdgcn_mfma_f32_32x32x16_f16(Ah3, Bh[3], acc, 0, 0, 0);
        acc = __builtin_amdgcn_mfma_f32_32x32x16_f16(Al3, Bh[3], acc, 0, 0, 0);
        acc = __builtin_amdgcn_mfma_f32_32x32x16_f16(Ah3, Bl[3], acc, 0, 0, 0);

        // per-lane argmin update over this lane's 16 code rows
        // n(r) = nt*32 + hi4 + (r&3) + 8*(r>>2) — increasing in (nt, r):
        // strict '>' keeps first (lowest index) maximum => first-min of distance
        const int nbase = nt * 32 + hi4;
#pragma unroll
        for (int r = 0; r < 16; ++r) {
            float m = acc[r];
            int   n = nbase + ((r & 3) + 8 * (r >> 2));
            if (m > maxv) { maxv = m; maxn = n; }
        }

        // write prefetched chunk into the other buffer (vmcnt drain lands
        // here, after compute), one barrier per nt
        if (nt < 15) {
            *(float4*)((char*)&As[p ^ 1][sHalf * 2048] + (tid & 255) * 16) = nf;
        }
        __syncthreads();
    }

    // ---- merge the two row-halves (lane <-> lane+32) ----
    {
        float ov = __shfl_xor(maxv, 32);
        int   on = __shfl_xor(maxn, 32);
        if (ov > maxv || (ov == maxv && on < maxn)) { maxv = ov; maxn = on; }
    }

    if (hi == 0) {
        Is[w * 32 + l31] = maxn;
        atomicAdd(&counts[c * MCODE + maxn], 1);
        outIdx[(size_t)(n0tk + w * 32 + l31) * NCB + c] = (float)maxn;
    }
    __syncthreads();

    // ---- quantized_st + loss (original fp32 emb + fp32 x for exactness) ----
    float lloss = 0.f;
#pragma unroll
    for (int i = 0; i < 8; ++i) {
        int q = tid + i * 512;
        int tok = q >> 4, d4 = q & 15;
        int idx = Is[tok];
        float mv = mask[(size_t)(n0tk + tok) * NCB + c];
        float4 e4 = *(const float4*)(emb + ((size_t)c * MCODE + idx) * DIM + d4 * 4);
        float4 x4 = *(const float4*)(x + (size_t)(n0tk + tok) * (NCB * DIM) + c * DIM + d4 * 4);
        float qx = e4.x * mv, qy = e4.y * mv, qz = e4.z * mv, qw = e4.w * mv;
        float4 o;
        o.x = x4.x + (qx - x4.x);
        o.y = x4.y + (qy - x4.y);
        o.z = x4.z + (qz - x4.z);
        o.w = x4.w + (qw - x4.w);
        *(float4*)(outQ + (size_t)(n0tk + tok) * (NCB * DIM) + c * DIM + d4 * 4) = o;
        float dx = x4.x - qx, dy = x4.y - qy, dz = x4.z - qz, dw = x4.w - qw;
        lloss += dx * dx + dy * dy + dz * dz + dw * dw;
    }
#pragma unroll
    for (int off = 32; off > 0; off >>= 1) lloss += __shfl_xor(lloss, off);
    if ((tid & 63) == 0) wls[tid >> 6] = lloss;
    __syncthreads();
    if (tid == 0) {
        float s = 0.f;
#pragma unroll
        for (int i = 0; i < 8; ++i) s += wls[i];
        atomicAdd(lossSum, s);
    }
}

__global__ __launch_bounds__(256) void finalize_kernel(const int* __restrict__ counts,
                                                       const float* __restrict__ lossSum,
                                                       float* __restrict__ out) {
    __shared__ float wls[4];
    int tid = threadIdx.x;
    float s = 0.f;
#pragma unroll
    for (int i = 0; i < 8; ++i) {
        int j = tid + i * 256;
        float p = (float)counts[j] * (1.0f / 65536.0f);
        s += p * logf(p + 1e-10f);
    }
#pragma unroll
    for (int off = 32; off > 0; off >>= 1) s += __shfl_xor(s, off);
    if ((tid & 63) == 0) wls[tid >> 6] = s;
    __syncthreads();
    if (tid == 0) {
        float tot = wls[0] + wls[1] + wls[2] + wls[3];
        float L = *lossSum * (1.0f / (float)QST_SIZE);
        out[QST_SIZE + 0] = 0.25f * L;   // commitment_loss
        out[QST_SIZE + 1] = L;           // codebook_loss
        out[QST_SIZE + 2] = expf(-tot);  // perplexity
    }
}

extern "C" void kernel_launch(void* const* d_in, const int* in_sizes, int n_in,
                              void* d_out, int out_size, void* d_ws, size_t ws_size,
                              hipStream_t stream) {
    const float* x    = (const float*)d_in[0];
    const float* emb  = (const float*)d_in[1];
    const float* mask = (const float*)d_in[2];
    float* out = (float*)d_out;

    _Float16* ehf  = (_Float16*)((char*)d_ws + WS_EH);
    _Float16* elf  = (_Float16*)((char*)d_ws + WS_EL);
    float* d0p     = (float*)((char*)d_ws + WS_D0);
    int*   counts  = (int*)((char*)d_ws + WS_CNT);
    float* lossSum = (float*)((char*)d_ws + WS_LOSS);

    prep_kernel<<<dim3(8), dim3(256), 0, stream>>>(emb, ehf, elf, d0p, counts, lossSum);
    vq_main<<<dim3(NTOK / TOK_TILE, NCB), dim3(512), 0, stream>>>(
        x, emb, mask, ehf, elf, d0p, counts, lossSum, out, out + IDX_OFF);
    finalize_kernel<<<dim3(1), dim3(256), 0, stream>>>(counts, lossSum, out);
}

// Round 8
// 198.477 us; speedup vs baseline: 1.0758x; 1.0758x over previous
//
#include <hip/hip_runtime.h>
#include <math.h>
#include <float.h>

// Problem constants
#define NTOK 65536
#define NCB  4
#define MCODE 512
#define DIM  64

#define QST_SIZE (NTOK * NCB * DIM)        // 16777216
#define IDX_OFF  (QST_SIZE + 3)            // 16777219

// Tiles: 4 waves/block, each wave owns 32 tokens (one 32-wide MFMA column tile)
#define TOK_TILE  128

// ws layout (bytes):
//   ehf f16[4*16*4*512] @ 0        (262144)  hi half of 512*e, MFMA-fragment order
//   elf f16[4*16*4*512] @ 262144   (262144)  lo half, fragment order
//   d0p f32[2048]       @ 524288   (8192)    -256 * sum(e^2)  (acc C-init)
//   counts int[2048]    @ 532480   (8192)
//   lossSum f32         @ 540672
#define WS_EH 0
#define WS_EL 262144
#define WS_D0 524288
#define WS_CNT 532480
#define WS_LOSS 540672

typedef _Float16 half8 __attribute__((ext_vector_type(8)));
typedef float floatx16 __attribute__((ext_vector_type(16)));

// ---- prep: wave-per-row fragment-order f16 hi/lo split of 512*e ----
// 2048 rows, 1 wave each -> 512 blocks x 256 thr (64x more parallel than the
// old 8-block thread-per-row version, which left 248 CUs idle).
// Lane d (0..63) owns element d of its row: coalesced 256B row load,
// shfl reduce for |e|^2, scattered-but-16B-grouped fragment stores.
// Fragment layout (A-operand, 32x32x16), element index d = ch*16 + h*8 + t:
//   off = ((c*16+nt)*4+ch)*512 + (h*32 + r5)*8 + t
__global__ __launch_bounds__(256) void prep_kernel(const float* __restrict__ emb,
                                                   _Float16* __restrict__ ehf,
                                                   _Float16* __restrict__ elf,
                                                   float* __restrict__ d0p,
                                                   int* __restrict__ counts,
                                                   float* __restrict__ lossSum) {
    const int tid  = threadIdx.x;
    const int lane = tid & 63;
    const int row  = blockIdx.x * 4 + (tid >> 6);   // 0..2047
    const int c    = row >> 9;
    const int n    = row & 511;
    const int nt   = n >> 5;
    const int r5   = n & 31;

    const float e = emb[(size_t)row * DIM + lane];

    // wave-reduce |e|^2
    float s = e * e;
#pragma unroll
    for (int off = 32; off > 0; off >>= 1) s += __shfl_xor(s, off);

    // hi/lo split of 512*e
    const float f = e * 512.0f;
    const _Float16 hv = (_Float16)f;
    const _Float16 lv = (_Float16)(f - (float)hv);

    const int ch = lane >> 4;
    const int h  = (lane >> 3) & 1;
    const int t  = lane & 7;
    const size_t off = ((size_t)((c * 16 + nt) * 4 + ch)) * 512 + (h * 32 + r5) * 8 + t;
    ehf[off] = hv;
    elf[off] = lv;

    if (lane == 0) {
        d0p[row] = -256.0f * s;
        counts[row] = 0;
        if (row == 0) *lossSum = 0.f;
    }
}

// ---- main: 32x32x16 MFMA + per-lane argmin; A staged through dbuf LDS ----
// (verbatim R5 kernel — best measured: 112.6 us, occ 35%, VGPR 64)
// A = codes (block-shared LDS stream), B = tokens (persistent, 32 VGPR).
// Per nt: prefetch chunk nt+1 global->regs (top), compute nt from LDS,
// ds_write regs->LDS[buf^1] (bottom), one barrier. 4x A-traffic reduction.
__global__ __launch_bounds__(256) void vq_main(const float* __restrict__ x,
                                               const float* __restrict__ emb,
                                               const float* __restrict__ mask,
                                               const _Float16* __restrict__ ehf,
                                               const _Float16* __restrict__ elf,
                                               const float* __restrict__ d0p,
                                               int* __restrict__ counts,
                                               float* __restrict__ lossSum,
                                               float* __restrict__ outQ,
                                               float* __restrict__ outIdx) {
    __shared__ __align__(16) _Float16 As[2][4096];   // [buf][eh 2048 | el 2048] = 16 KB
    __shared__ __align__(16) float d0s[MCODE];       // 2 KB
    __shared__ int   Is[TOK_TILE];
    __shared__ float wls[4];

    const int tid  = threadIdx.x;
    const int c    = blockIdx.y;
    const int n0tk = blockIdx.x * TOK_TILE;
    const int lane = tid & 63;
    const int w    = tid >> 6;            // wave id 0..3
    const int l31  = lane & 31;           // token within wave tile / acc column
    const int hi   = lane >> 5;           // k-half for A/B, row-half for C
    const int hi4  = hi * 4;

    const _Float16* gEh = ehf + (size_t)c * (16 * 4 * 512);
    const _Float16* gEl = elf + (size_t)c * (16 * 4 * 512);

    // ---- stage chunk 0 + d0 into LDS (loads first, for overlap with B-build) ----
    float4 sh = *(const float4*)(gEh + tid * 8);
    float4 sl = *(const float4*)(gEl + tid * 8);
    float4 dstage;
    if (tid < 128) dstage = *(const float4*)(d0p + c * MCODE + tid * 4);

    // ---- persistent B fragments (x hi/lo) for this lane's token ----
    // B col = lane&31 = token; k = ch*16 + hi*8 + t
    half8 Bh[4], Bl[4];
    {
        const float* xr = x + (size_t)(n0tk + w * 32 + l31) * (NCB * DIM) + c * DIM + hi * 8;
#pragma unroll
        for (int ch = 0; ch < 4; ++ch) {
            float fv[8];
            *(float4*)(fv)     = *(const float4*)(xr + ch * 16);
            *(float4*)(fv + 4) = *(const float4*)(xr + ch * 16 + 4);
            half8 h8, l8;
#pragma unroll
            for (int t = 0; t < 8; ++t) {
                float f = fv[t];
                _Float16 hh = (_Float16)f;
                h8[t] = hh;
                l8[t] = (_Float16)(f - (float)hh);
            }
            Bh[ch] = h8;
            Bl[ch] = l8;
        }
    }

    *(float4*)((char*)&As[0][0]    + tid * 16) = sh;
    *(float4*)((char*)&As[0][2048] + tid * 16) = sl;
    if (tid < 128) *(float4*)(&d0s[tid * 4]) = dstage;
    __syncthreads();

    float maxv = -FLT_MAX;
    int   maxn = 0;

    // ---- sweep 16 n-tiles of 32 codes, dbuf LDS + 1-ahead prefetch ----
    for (int nt = 0; nt < 16; ++nt) {
        const int p = nt & 1;

        // prefetch next chunk to regs (latency hides under MFMA+argmin below)
        float4 nh, nl;
        if (nt < 15) {
            nh = *(const float4*)(gEh + (nt + 1) * 2048 + tid * 8);
            nl = *(const float4*)(gEl + (nt + 1) * 2048 + tid * 8);
        }

        // A fragment reads from LDS (stride-1 b128, standard pattern)
        const _Float16* ah = &As[p][0] + lane * 8;
        const _Float16* al = &As[p][2048] + lane * 8;
        half8 Ah0 = *(const half8*)(ah);
        half8 Ah1 = *(const half8*)(ah + 512);
        half8 Ah2 = *(const half8*)(ah + 1024);
        half8 Ah3 = *(const half8*)(ah + 1536);
        half8 Al0 = *(const half8*)(al);
        half8 Al1 = *(const half8*)(al + 512);
        half8 Al2 = *(const half8*)(al + 1024);
        half8 Al3 = *(const half8*)(al + 1536);

        // acc C-init = -256*|e|^2 per code row (LDS broadcast reads)
        const float* dpt = &d0s[nt * 32 + hi4];
        float4 d40 = *(const float4*)(dpt);
        float4 d41 = *(const float4*)(dpt + 8);
        float4 d42 = *(const float4*)(dpt + 16);
        float4 d43 = *(const float4*)(dpt + 24);
        floatx16 acc;
        acc[0]  = d40.x; acc[1]  = d40.y; acc[2]  = d40.z; acc[3]  = d40.w;
        acc[4]  = d41.x; acc[5]  = d41.y; acc[6]  = d41.z; acc[7]  = d41.w;
        acc[8]  = d42.x; acc[9]  = d42.y; acc[10] = d42.z; acc[11] = d42.w;
        acc[12] = d43.x; acc[13] = d43.y; acc[14] = d43.z; acc[15] = d43.w;

        // 12-MFMA chain: (Ah+Al)(Bh+Bl) ≈ AhBh + AlBh + AhBl per k-chunk
        acc = __builtin_amdgcn_mfma_f32_32x32x16_f16(Ah0, Bh[0], acc, 0, 0, 0);
        acc = __builtin_amdgcn_mfma_f32_32x32x16_f16(Al0, Bh[0], acc, 0, 0, 0);
        acc = __builtin_amdgcn_mfma_f32_32x32x16_f16(Ah0, Bl[0], acc, 0, 0, 0);
        acc = __builtin_amdgcn_mfma_f32_32x32x16_f16(Ah1, Bh[1], acc, 0, 0, 0);
        acc = __builtin_amdgcn_mfma_f32_32x32x16_f16(Al1, Bh[1], acc, 0, 0, 0);
        acc = __builtin_amdgcn_mfma_f32_32x32x16_f16(Ah1, Bl[1], acc, 0, 0, 0);
        acc = __builtin_amdgcn_mfma_f32_32x32x16_f16(Ah2, Bh[2], acc, 0, 0, 0);
        acc = __builtin_amdgcn_mfma_f32_32x32x16_f16(Al2, Bh[2], acc, 0, 0, 0);
        acc = __builtin_amdgcn_mfma_f32_32x32x16_f16(Ah2, Bl[2], acc, 0, 0, 0);
        acc = __builtin_amdgcn_mfma_f32_32x32x16_f16(Ah3, Bh[3], acc, 0, 0, 0);
        acc = __builtin_amdgcn_mfma_f32_32x32x16_f16(Al3, Bh[3], acc, 0, 0, 0);
        acc = __builtin_amdgcn_mfma_f32_32x32x16_f16(Ah3, Bl[3], acc, 0, 0, 0);

        // per-lane argmin update over this lane's 16 code rows
        // row(r) = (r&3) + 8*(r>>2) + hi4 + nt*32 — increasing in (nt, r):
        // strict '>' keeps first (lowest index) maximum => first-min of distance
        const int nbase = nt * 32 + hi4;
#pragma unroll
        for (int r = 0; r < 16; ++r) {
            float m = acc[r];
            int   n = nbase + ((r & 3) + 8 * (r >> 2));
            if (m > maxv) { maxv = m; maxn = n; }
        }

        // write prefetched chunk into the other buffer (forces vmcnt wait here,
        // after compute), then one barrier ends the iteration
        if (nt < 15) {
            *(float4*)((char*)&As[p ^ 1][0]    + tid * 16) = nh;
            *(float4*)((char*)&As[p ^ 1][2048] + tid * 16) = nl;
        }
        __syncthreads();
    }

    // ---- merge the two row-halves (lane <-> lane+32) ----
    {
        float ov = __shfl_xor(maxv, 32);
        int   on = __shfl_xor(maxn, 32);
        if (ov > maxv || (ov == maxv && on < maxn)) { maxv = ov; maxn = on; }
    }

    if (hi == 0) {
        Is[w * 32 + l31] = maxn;
        atomicAdd(&counts[c * MCODE + maxn], 1);
        outIdx[(size_t)(n0tk + w * 32 + l31) * NCB + c] = (float)maxn;
    }
    __syncthreads();

    // ---- quantized_st + loss (original fp32 emb + fp32 x for exactness) ----
    float lloss = 0.f;
#pragma unroll
    for (int i = 0; i < 8; ++i) {
        int q = tid + i * 256;
        int tok = q >> 4, d4 = q & 15;
        int idx = Is[tok];
        float mv = mask[(size_t)(n0tk + tok) * NCB + c];
        float4 e4 = *(const float4*)(emb + ((size_t)c * MCODE + idx) * DIM + d4 * 4);
        float4 x4 = *(const float4*)(x + (size_t)(n0tk + tok) * (NCB * DIM) + c * DIM + d4 * 4);
        float qx = e4.x * mv, qy = e4.y * mv, qz = e4.z * mv, qw = e4.w * mv;
        float4 o;
        o.x = x4.x + (qx - x4.x);
        o.y = x4.y + (qy - x4.y);
        o.z = x4.z + (qz - x4.z);
        o.w = x4.w + (qw - x4.w);
        *(float4*)(outQ + (size_t)(n0tk + tok) * (NCB * DIM) + c * DIM + d4 * 4) = o;
        float dx = x4.x - qx, dy = x4.y - qy, dz = x4.z - qz, dw = x4.w - qw;
        lloss += dx * dx + dy * dy + dz * dz + dw * dw;
    }
#pragma unroll
    for (int off = 32; off > 0; off >>= 1) lloss += __shfl_xor(lloss, off);
    if ((tid & 63) == 0) wls[tid >> 6] = lloss;
    __syncthreads();
    if (tid == 0) {
        float s = wls[0] + wls[1] + wls[2] + wls[3];
        atomicAdd(lossSum, s);
    }
}

__global__ __launch_bounds__(256) void finalize_kernel(const int* __restrict__ counts,
                                                       const float* __restrict__ lossSum,
                                                       float* __restrict__ out) {
    __shared__ float wls[4];
    int tid = threadIdx.x;
    float s = 0.f;
#pragma unroll
    for (int i = 0; i < 8; ++i) {
        int j = tid + i * 256;
        float p = (float)counts[j] * (1.0f / 65536.0f);
        s += p * logf(p + 1e-10f);
    }
#pragma unroll
    for (int off = 32; off > 0; off >>= 1) s += __shfl_xor(s, off);
    if ((tid & 63) == 0) wls[tid >> 6] = s;
    __syncthreads();
    if (tid == 0) {
        float tot = wls[0] + wls[1] + wls[2] + wls[3];
        float L = *lossSum * (1.0f / (float)QST_SIZE);
        out[QST_SIZE + 0] = 0.25f * L;   // commitment_loss
        out[QST_SIZE + 1] = L;           // codebook_loss
        out[QST_SIZE + 2] = expf(-tot);  // perplexity
    }
}

extern "C" void kernel_launch(void* const* d_in, const int* in_sizes, int n_in,
                              void* d_out, int out_size, void* d_ws, size_t ws_size,
                              hipStream_t stream) {
    const float* x    = (const float*)d_in[0];
    const float* emb  = (const float*)d_in[1];
    const float* mask = (const float*)d_in[2];
    float* out = (float*)d_out;

    _Float16* ehf  = (_Float16*)((char*)d_ws + WS_EH);
    _Float16* elf  = (_Float16*)((char*)d_ws + WS_EL);
    float* d0p     = (float*)((char*)d_ws + WS_D0);
    int*   counts  = (int*)((char*)d_ws + WS_CNT);
    float* lossSum = (float*)((char*)d_ws + WS_LOSS);

    prep_kernel<<<dim3(512), dim3(256), 0, stream>>>(emb, ehf, elf, d0p, counts, lossSum);
    vq_main<<<dim3(NTOK / TOK_TILE, NCB), dim3(256), 0, stream>>>(
        x, emb, mask, ehf, elf, d0p, counts, lossSum, out, out + IDX_OFF);
    finalize_kernel<<<dim3(1), dim3(256), 0, stream>>>(counts, lossSum, out);
}